// Round 12
// baseline (1332.788 us; speedup 1.0000x reference)
//
#include <hip/hip_runtime.h>

#define B_ 64
#define S_ 2048
#define D_ 64
#define H_ 128
#define G_ 512
#define CH 16
#define T_ 256

typedef float f32x4 __attribute__((ext_vector_type(4)));
typedef short bf16x8 __attribute__((ext_vector_type(8)));

#define MFMA16(a, b, c) __builtin_amdgcn_mfma_f32_16x16x32_bf16((a), (b), (c), 0, 0, 0)
#define RCPF(x) __builtin_amdgcn_rcpf(x)
#define LOG2E 1.442695041f

#if __has_builtin(__builtin_amdgcn_exp2f)
#define EXP2(x) __builtin_amdgcn_exp2f(x)
#else
#define EXP2(x) exp2f(x)
#endif

// Per-step barrier: drain LDS, HW barrier, zero-cost compiler memory fence.
// (R7/R8-proven; keeps global prefetch in flight, no scheduler pinning.)
#define STEP_SYNC() do {                                  \
    asm volatile("s_waitcnt lgkmcnt(0)" ::: "memory");    \
    __builtin_amdgcn_s_barrier();                         \
    asm volatile("" ::: "memory");                        \
} while (0)

__device__ __forceinline__ short f2bf(float f) {
    unsigned u = __builtin_bit_cast(unsigned, f);
    return (short)((u + 0x7FFFu + ((u >> 16) & 1u)) >> 16);  // RNE
}
__device__ __forceinline__ float bflo(unsigned u) { return __builtin_bit_cast(float, u << 16); }
__device__ __forceinline__ float bfhi(unsigned u) { return __builtin_bit_cast(float, u & 0xFFFF0000u); }
__device__ __forceinline__ float sigm_f(float x) { return RCPF(1.0f + EXP2(x * -LOG2E)); }

// One block per batch element; 256 threads = 4 waves (1 wave per SIMD).
// Wave w owns hidden units [32w, 32w+32): per lane (l4,l15) two units
// uA = 32w+l15, uB = 32w+16+l15; 8 persistent MFMA acc chains (2 units x 4
// gates), 32 MFMA/wave/step (same 128/CU issue floor as the 8-wave R8, but
// half the LDS instructions, half the barrier participants, no intra-SIMD
// wave contention). Weights prescaled by -log2e (-2log2e for g-gate) so the
// gate chains feed exp2 directly. Wx^T lives prescaled-bf16 in LDS (padded
// to 72 for bank spread + 16B alignment: 72*2=144=9*16).
__launch_bounds__(256, 1)
__global__ void lstm_fused(const float* __restrict__ x, const float* __restrict__ Wx,
                           const float* __restrict__ Wh, const float* __restrict__ bias,
                           const float* __restrict__ Wd, const float* __restrict__ bd,
                           float* __restrict__ out) {
    const int tid = threadIdx.x;
    const int lane = tid & 63;
    const int wid = tid >> 6;      // 0..3
    const int l15 = lane & 15;
    const int l4 = lane >> 4;      // 0..3
    const int bb = blockIdx.x;

    __shared__ alignas(16) short wxt[G_][72];    // prescaled bf16 Wx^T (72KB)
    __shared__ alignas(16) float xzc[CH][G_];    // [tm][unit*4+gate] (32KB)
    __shared__ alignas(16) short hist[CH][H_];   // h ring (bf16) (4KB)
    __shared__ alignas(16) short xbf[CH][72];    // x chunk (padded) (2.3KB)

    // zero hist: 1024 dwords / 256 threads
    {
        unsigned* hz = (unsigned*)hist;
        hz[tid] = 0u; hz[tid + 256] = 0u; hz[tid + 512] = 0u; hz[tid + 768] = 0u;
    }
    // prescaled Wx^T: wxt[col][row] = Wx[row][col] * msc(gate(col))
    for (int i = tid; i < G_ * D_; i += T_) {
        const int colx = i & (G_ - 1);
        const int row = i >> 9;
        const float ms = ((colx >> 7) == 2) ? (-2.0f * LOG2E) : (-LOG2E);
        wxt[colx][row] = f2bf(Wx[i] * ms);
    }

    // --- prescaled Wh B-fragments: 8 col-tiles (hh,g) x 4 k-tiles ---
    // j = hh*4 + g ; col = g*128 + wid*32 + hh*16 + l15 ; k = kt*32 + l4*8 + e
    bf16x8 bh[8][4];
    float bvr[8];
#pragma unroll
    for (int hh = 0; hh < 2; ++hh) {
#pragma unroll
        for (int g = 0; g < 4; ++g) {
            const float msc = (g == 2) ? (-2.0f * LOG2E) : (-LOG2E);
            const int col = g * H_ + wid * 32 + hh * 16 + l15;
            bvr[hh * 4 + g] = bias[col] * msc;
#pragma unroll
            for (int kt = 0; kt < 4; ++kt) {
                bf16x8 v;
#pragma unroll
                for (int e = 0; e < 8; ++e)
                    v[e] = f2bf(Wh[(kt * 32 + l4 * 8 + e) * G_ + col] * msc);
                bh[hh * 4 + g][kt] = v;
            }
        }
    }

    const float wd0 = Wd[lane * 2 + 0];
    const float wd1 = Wd[lane * 2 + 1];
    const float bdv = bd[0];
    float cA = 0.0f, cB = 0.0f;   // fp32 cell states (replicated across l4)

    const float* xb = x + (size_t)bb * S_ * D_;
    float* ob = out + (size_t)bb * S_;

    // prefetch x chunk 0: 4 floats/thread (16x64 = 1024)
    float xp0 = xb[tid * 4 + 0], xp1 = xb[tid * 4 + 1];
    float xp2 = xb[tid * 4 + 2], xp3 = xb[tid * 4 + 3];

    // persistent acc chains: only reg 0 meaningful (rows 1-3 stale, bounded)
    f32x4 acc[8];
#pragma unroll
    for (int j = 0; j < 8; ++j) acc[j] = (f32x4){0.f, 0.f, 0.f, 0.f};

    for (int tc = 0; tc < S_; tc += CH) {
        // commit prefetched x chunk (row = tid>>4, 4 consecutive elems)
        {
            short* xr = &xbf[tid >> 4][(tid & 15) * 4];
            xr[0] = f2bf(xp0); xr[1] = f2bf(xp1); xr[2] = f2bf(xp2); xr[3] = f2bf(xp3);
        }
        __syncthreads();   // xbf + (first iter) wxt/hist ready
        if (tc + CH < S_) {
            xp0 = xb[(tc + CH) * D_ + tid * 4 + 0];
            xp1 = xb[(tc + CH) * D_ + tid * 4 + 1];
            xp2 = xb[(tc + CH) * D_ + tid * 4 + 2];
            xp3 = xb[(tc + CH) * D_ + tid * 4 + 3];
        }
        // xz_chunk = X[16x64] @ Wx + b (prescaled) -> [tm][unit*4+gate]
#pragma unroll
        for (int hh = 0; hh < 2; ++hh) {
#pragma unroll
            for (int g = 0; g < 4; ++g) {
                const int col = g * H_ + wid * 32 + hh * 16 + l15;
                const float bv = bvr[hh * 4 + g];
                f32x4 cc = {bv, bv, bv, bv};
#pragma unroll
                for (int kt = 0; kt < 2; ++kt) {
                    const bf16x8 a = *reinterpret_cast<const bf16x8*>(
                        &xbf[l15][kt * 32 + l4 * 8]);
                    const bf16x8 b = *reinterpret_cast<const bf16x8*>(
                        &wxt[col][kt * 32 + l4 * 8]);
                    cc = MFMA16(a, b, cc);
                }
                const int unit = wid * 32 + hh * 16 + l15;
#pragma unroll
                for (int r = 0; r < 4; ++r)
                    xzc[l4 * 4 + r][unit * 4 + g] = cc[r];   // D row=(lane>>4)*4+r [m89]
            }
        }
        // dense head for the PREVIOUS chunk (4 rows per wave)
        if (tc > 0) {
#pragma unroll
            for (int s = 0; s < 4; ++s) {
                const int row = wid * 4 + s;
                const unsigned hp = *reinterpret_cast<const unsigned*>(&hist[row][lane * 2]);
                float p = bflo(hp) * wd0 + bfhi(hp) * wd1;
                p += __shfl_xor(p, 1);  p += __shfl_xor(p, 2);  p += __shfl_xor(p, 4);
                p += __shfl_xor(p, 8);  p += __shfl_xor(p, 16); p += __shfl_xor(p, 32);
                if (lane == 0) ob[tc - CH + row] = sigm_f(p + bdv);
            }
        }
        __syncthreads();   // xzc ready; hist fully consumed before overwrite

#pragma unroll
        for (int tm = 0; tm < CH; ++tm) {
            const int prev = (tm + CH - 1) & (CH - 1);
            const short* hsrc = hist[prev];
            const bf16x8 a0 = *reinterpret_cast<const bf16x8*>(&hsrc[ 0 + l4 * 8]);
            const bf16x8 a1 = *reinterpret_cast<const bf16x8*>(&hsrc[32 + l4 * 8]);
            const bf16x8 a2 = *reinterpret_cast<const bf16x8*>(&hsrc[64 + l4 * 8]);
            const bf16x8 a3 = *reinterpret_cast<const bf16x8*>(&hsrc[96 + l4 * 8]);
            const int uA = wid * 32 + l15;
            const f32x4 xzA = *reinterpret_cast<const f32x4*>(&xzc[tm][uA * 4]);
            const f32x4 xzB = *reinterpret_cast<const f32x4*>(&xzc[tm][(uA + 16) * 4]);

            // init only reg 0 of each chain (row l4*4 is the only row read)
            acc[0][0] = xzA[0];  acc[1][0] = xzA[1];
            acc[2][0] = xzA[2];  acc[3][0] = xzA[3];
            acc[4][0] = xzB[0];  acc[5][0] = xzB[1];
            acc[6][0] = xzB[2];  acc[7][0] = xzB[3];

#pragma unroll
            for (int j = 0; j < 8; ++j) acc[j] = MFMA16(a0, bh[j][0], acc[j]);
#pragma unroll
            for (int j = 0; j < 8; ++j) acc[j] = MFMA16(a1, bh[j][1], acc[j]);
#pragma unroll
            for (int j = 0; j < 8; ++j) acc[j] = MFMA16(a2, bh[j][2], acc[j]);
#pragma unroll
            for (int j = 0; j < 8; ++j) acc[j] = MFMA16(a3, bh[j][3], acc[j]);

            // gates for unit A (prescaled z feeds exp2 directly)
            const float ivA = RCPF(1.0f + EXP2(acc[0][0]));
            const float fvA = RCPF(1.0f + EXP2(acc[1][0]));
            const float gvA = __builtin_fmaf(2.0f, RCPF(1.0f + EXP2(acc[2][0])), -1.0f);
            const float ovA = RCPF(1.0f + EXP2(acc[3][0]));
            cA = __builtin_fmaf(fvA, cA, ivA * gvA);
            const float thA = __builtin_fmaf(
                2.0f, RCPF(1.0f + EXP2(cA * (-2.0f * LOG2E))), -1.0f);
            const float hvA = ovA * thA;

            // gates for unit B
            const float ivB = RCPF(1.0f + EXP2(acc[4][0]));
            const float fvB = RCPF(1.0f + EXP2(acc[5][0]));
            const float gvB = __builtin_fmaf(2.0f, RCPF(1.0f + EXP2(acc[6][0])), -1.0f);
            const float ovB = RCPF(1.0f + EXP2(acc[7][0]));
            cB = __builtin_fmaf(fvB, cB, ivB * gvB);
            const float thB = __builtin_fmaf(
                2.0f, RCPF(1.0f + EXP2(cB * (-2.0f * LOG2E))), -1.0f);
            const float hvB = ovB * thB;

            if (l4 == 0)      hist[tm][uA]      = f2bf(hvA);
            else if (l4 == 1) hist[tm][uA + 16] = f2bf(hvB);
            STEP_SYNC();   // h_t visible to all waves for step t+1
        }
    }

    // dense head for the final chunk
#pragma unroll
    for (int s = 0; s < 4; ++s) {
        const int row = wid * 4 + s;
        const unsigned hp = *reinterpret_cast<const unsigned*>(&hist[row][lane * 2]);
        float p = bflo(hp) * wd0 + bfhi(hp) * wd1;
        p += __shfl_xor(p, 1);  p += __shfl_xor(p, 2);  p += __shfl_xor(p, 4);
        p += __shfl_xor(p, 8);  p += __shfl_xor(p, 16); p += __shfl_xor(p, 32);
        if (lane == 0) ob[S_ - CH + row] = sigm_f(p + bdv);
    }
}

extern "C" void kernel_launch(void* const* d_in, const int* in_sizes, int n_in,
                              void* d_out, int out_size, void* d_ws, size_t ws_size,
                              hipStream_t stream) {
    const float* x  = (const float*)d_in[0];
    const float* Wx = (const float*)d_in[1];
    const float* Wh = (const float*)d_in[2];
    const float* b  = (const float*)d_in[3];
    const float* Wd = (const float*)d_in[4];
    const float* bd = (const float*)d_in[5];
    float* out = (float*)d_out;

    lstm_fused<<<B_, T_, 0, stream>>>(x, Wx, Wh, b, Wd, bd, out);
}

// Round 13
// 884.141 us; speedup vs baseline: 1.5074x; 1.5074x over previous
//
#include <hip/hip_runtime.h>

#define B_ 64
#define S_ 2048
#define D_ 64
#define H_ 128
#define G_ 512
#define CH 16

typedef float f32x4 __attribute__((ext_vector_type(4)));
typedef short bf16x8 __attribute__((ext_vector_type(8)));

#define MFMA16(a, b, c) __builtin_amdgcn_mfma_f32_16x16x32_bf16((a), (b), (c), 0, 0, 0)
#define RCPF(x) __builtin_amdgcn_rcpf(x)
#define LOG2E 1.442695041f

#if __has_builtin(__builtin_amdgcn_exp2f)
#define EXP2(x) __builtin_amdgcn_exp2f(x)
#else
#define EXP2(x) exp2f(x)
#endif

// Per-step barrier: drain LDS, HW barrier, zero-cost compiler memory fence.
// (R7/R8-proven; keeps global prefetch in flight, no scheduler pinning.)
#define STEP_SYNC() do {                                  \
    asm volatile("s_waitcnt lgkmcnt(0)" ::: "memory");    \
    __builtin_amdgcn_s_barrier();                         \
    asm volatile("" ::: "memory");                        \
} while (0)

__device__ __forceinline__ short f2bf(float f) {
    unsigned u = __builtin_bit_cast(unsigned, f);
    return (short)((u + 0x7FFFu + ((u >> 16) & 1u)) >> 16);  // RNE
}
__device__ __forceinline__ float bflo(unsigned u) { return __builtin_bit_cast(float, u << 16); }
__device__ __forceinline__ float bfhi(unsigned u) { return __builtin_bit_cast(float, u & 0xFFFF0000u); }
__device__ __forceinline__ float sigm_f(float x) { return RCPF(1.0f + EXP2(x * -LOG2E)); }

// One block per batch element; 512 threads = 8 waves, 2/SIMD (R12 lesson:
// the co-resident wave hides the serial tail; 1 wave/SIMD exposes it).
// Wave w owns hidden units [16w,16w+16); all-gates-per-lane (R8).
// Weights prescaled by -log2e (-2log2e for g) so gate chains feed exp2
// directly (R9-proven). xz for the whole chunk is HOISTED to registers at
// chunk start (16 x f32x4): the STEP_SYNC "memory" clobber blocks the
// compiler from hoisting LDS reads itself, so do it manually — removes
// 1 ds_read_b128/lane/step from the post-barrier LDS burst.
__launch_bounds__(512, 1)
__global__ void lstm_fused(const float* __restrict__ x, const float* __restrict__ Wx,
                           const float* __restrict__ Wh, const float* __restrict__ bias,
                           const float* __restrict__ Wd, const float* __restrict__ bd,
                           float* __restrict__ out) {
    const int tid = threadIdx.x;
    const int lane = tid & 63;
    const int wid = tid >> 6;      // 0..7
    const int l15 = lane & 15;
    const int l4 = lane >> 4;      // 0..3
    const int bb = blockIdx.x;

    __shared__ alignas(16) short hist[CH][H_];   // h ring (bf16), slot = t & 15
    __shared__ alignas(16) short xbf[CH][72];    // x chunk (padded)
    __shared__ alignas(16) float xzc[CH][G_];    // [tm][unit*4+gate], prescaled

    ((unsigned*)hist)[tid] = 0u;
    ((unsigned*)hist)[tid + 512] = 0u;

    const int col0 = wid * 16 + l15;             // hidden unit

    // --- prescaled Wh B-fragments, col = gate*128 + col0, k = kt*32+l4*8+e ---
    bf16x8 bh[4][4];
#pragma unroll
    for (int ct = 0; ct < 4; ++ct) {
        const float msc = (ct == 2) ? (-2.0f * LOG2E) : (-LOG2E);
        const int col = ct * H_ + col0;
#pragma unroll
        for (int kt = 0; kt < 4; ++kt) {
            bf16x8 v;
#pragma unroll
            for (int e = 0; e < 8; ++e)
                v[e] = f2bf(Wh[(kt * 32 + l4 * 8 + e) * G_ + col] * msc);
            bh[ct][kt] = v;
        }
    }
    // --- prescaled Wx B-fragments ---
    bf16x8 bx[4][2];
#pragma unroll
    for (int ct = 0; ct < 4; ++ct) {
        const float msc = (ct == 2) ? (-2.0f * LOG2E) : (-LOG2E);
        const int col = ct * H_ + col0;
#pragma unroll
        for (int kt = 0; kt < 2; ++kt) {
            bf16x8 v;
#pragma unroll
            for (int e = 0; e < 8; ++e)
                v[e] = f2bf(Wx[(kt * 32 + l4 * 8 + e) * G_ + col] * msc);
            bx[ct][kt] = v;
        }
    }

    float bvr[4];
#pragma unroll
    for (int ct = 0; ct < 4; ++ct)
        bvr[ct] = bias[ct * H_ + col0] * ((ct == 2) ? (-2.0f * LOG2E) : (-LOG2E));
    const float wd0 = Wd[lane * 2 + 0];
    const float wd1 = Wd[lane * 2 + 1];
    const float bdv = bd[0];
    float c_reg = 0.0f;

    const float* xb = x + (size_t)bb * S_ * D_;
    float* ob = out + (size_t)bb * S_;

    float xp0 = xb[tid * 2 + 0];
    float xp1 = xb[tid * 2 + 1];

    // persistent acc chains: only reg 0 meaningful (rows 1-3 stale, bounded)
    f32x4 acc0 = {0.f, 0.f, 0.f, 0.f}, acc1 = acc0, acc2 = acc0, acc3 = acc0;

    for (int tc = 0; tc < S_; tc += CH) {
        // commit prefetched x chunk (data dep forces the vmcnt wait here)
        xbf[tid >> 5][(tid & 31) * 2 + 0] = f2bf(xp0);
        xbf[tid >> 5][(tid & 31) * 2 + 1] = f2bf(xp1);
        __syncthreads();
        if (tc + CH < S_) {
            xp0 = xb[(tc + CH) * D_ + tid * 2 + 0];
            xp1 = xb[(tc + CH) * D_ + tid * 2 + 1];
        }
        // xz_chunk = X[16x64] @ Wx + b (prescaled) -> [tm][unit*4+gate]
#pragma unroll
        for (int ct = 0; ct < 4; ++ct) {
            f32x4 cc = {bvr[ct], bvr[ct], bvr[ct], bvr[ct]};
#pragma unroll
            for (int kt = 0; kt < 2; ++kt) {
                const bf16x8 a = *reinterpret_cast<const bf16x8*>(&xbf[l15][kt * 32 + l4 * 8]);
                cc = MFMA16(a, bx[ct][kt], cc);
            }
#pragma unroll
            for (int r = 0; r < 4; ++r)
                xzc[l4 * 4 + r][col0 * 4 + ct] = cc[r];   // D row = (lane>>4)*4+r [m89]
        }
        // dense head for the PREVIOUS chunk (hist = h_{tc-16..tc-1})
        if (tc > 0) {
#pragma unroll
            for (int s = 0; s < 2; ++s) {
                const int row = wid * 2 + s;
                const unsigned hp = *reinterpret_cast<const unsigned*>(&hist[row][lane * 2]);
                float p = bflo(hp) * wd0 + bfhi(hp) * wd1;
                p += __shfl_xor(p, 1);  p += __shfl_xor(p, 2);  p += __shfl_xor(p, 4);
                p += __shfl_xor(p, 8);  p += __shfl_xor(p, 16); p += __shfl_xor(p, 32);
                if (lane == 0) ob[tc - CH + row] = sigm_f(p + bdv);
            }
        }
        __syncthreads();   // xzc ready; hist fully consumed before overwrite

        // HOIST: this lane's xz for all 16 steps -> 16 f32x4 in registers.
        // (static indexing below keeps these out of scratch — rule #20)
        f32x4 xzr[CH];
#pragma unroll
        for (int j = 0; j < CH; ++j)
            xzr[j] = *reinterpret_cast<const f32x4*>(&xzc[j][col0 * 4]);

#pragma unroll
        for (int tm = 0; tm < CH; ++tm) {
            const int prev = (tm + CH - 1) & (CH - 1);
            const short* hsrc = hist[prev];
            const bf16x8 a0 = *reinterpret_cast<const bf16x8*>(&hsrc[ 0 + l4 * 8]);
            const bf16x8 a1 = *reinterpret_cast<const bf16x8*>(&hsrc[32 + l4 * 8]);
            const bf16x8 a2 = *reinterpret_cast<const bf16x8*>(&hsrc[64 + l4 * 8]);
            const bf16x8 a3 = *reinterpret_cast<const bf16x8*>(&hsrc[96 + l4 * 8]);

            // init only reg 0 of each chain (row l4*4 is the only row read)
            acc0[0] = xzr[tm][0];  acc1[0] = xzr[tm][1];
            acc2[0] = xzr[tm][2];  acc3[0] = xzr[tm][3];

            acc0 = MFMA16(a0, bh[0][0], acc0);
            acc1 = MFMA16(a0, bh[1][0], acc1);
            acc2 = MFMA16(a0, bh[2][0], acc2);
            acc3 = MFMA16(a0, bh[3][0], acc3);
            acc0 = MFMA16(a1, bh[0][1], acc0);
            acc1 = MFMA16(a1, bh[1][1], acc1);
            acc2 = MFMA16(a1, bh[2][1], acc2);
            acc3 = MFMA16(a1, bh[3][1], acc3);
            acc0 = MFMA16(a2, bh[0][2], acc0);
            acc1 = MFMA16(a2, bh[1][2], acc1);
            acc2 = MFMA16(a2, bh[2][2], acc2);
            acc3 = MFMA16(a2, bh[3][2], acc3);
            acc0 = MFMA16(a3, bh[0][3], acc0);
            acc1 = MFMA16(a3, bh[1][3], acc1);
            acc2 = MFMA16(a3, bh[2][3], acc2);
            acc3 = MFMA16(a3, bh[3][3], acc3);

            // gates (prescaled z feeds exp2 directly)
            const float iv = RCPF(1.0f + EXP2(acc0[0]));
            const float fv = RCPF(1.0f + EXP2(acc1[0]));
            const float gv = __builtin_fmaf(2.0f, RCPF(1.0f + EXP2(acc2[0])), -1.0f);
            const float ov = RCPF(1.0f + EXP2(acc3[0]));

            c_reg = __builtin_fmaf(fv, c_reg, iv * gv);
            const float th = __builtin_fmaf(
                2.0f, RCPF(1.0f + EXP2(c_reg * (-2.0f * LOG2E))), -1.0f);
            const float hv = ov * th;

            if (lane < 16) hist[tm][col0] = f2bf(hv);
            STEP_SYNC();   // h_t visible to all waves for step t+1
        }
    }

    // dense head for the final 16 steps
#pragma unroll
    for (int s = 0; s < 2; ++s) {
        const int row = wid * 2 + s;
        const unsigned hp = *reinterpret_cast<const unsigned*>(&hist[row][lane * 2]);
        float p = bflo(hp) * wd0 + bfhi(hp) * wd1;
        p += __shfl_xor(p, 1);  p += __shfl_xor(p, 2);  p += __shfl_xor(p, 4);
        p += __shfl_xor(p, 8);  p += __shfl_xor(p, 16); p += __shfl_xor(p, 32);
        if (lane == 0) ob[S_ - CH + row] = sigm_f(p + bdv);
    }
}

extern "C" void kernel_launch(void* const* d_in, const int* in_sizes, int n_in,
                              void* d_out, int out_size, void* d_ws, size_t ws_size,
                              hipStream_t stream) {
    const float* x  = (const float*)d_in[0];
    const float* Wx = (const float*)d_in[1];
    const float* Wh = (const float*)d_in[2];
    const float* b  = (const float*)d_in[3];
    const float* Wd = (const float*)d_in[4];
    const float* bd = (const float*)d_in[5];
    float* out = (float*)d_out;

    lstm_fused<<<B_, 512, 0, stream>>>(x, Wx, Wh, b, Wd, bd, out);
}